// Round 9
// baseline (691.021 us; speedup 1.0000x reference)
//
#include <hip/hip_runtime.h>
#include <hip/hip_bf16.h>
#include <cstdint>
#include <cstddef>

#define N_NODES 100000
#define NFEAT 512
#define NHID 256
#define NCLASS 128
#define K_HOPS 5
#define ALPHA 0.1f

typedef __attribute__((ext_vector_type(8))) short short8v;   // 8 bf16 (4 VGPRs)
typedef __attribute__((ext_vector_type(4))) float f32x4;     // MFMA accumulator

__device__ __forceinline__ unsigned short f2bf(float f) {
    unsigned u = __builtin_bit_cast(unsigned, f);
    u += 0x7FFFu + ((u >> 16) & 1u);      // round-to-nearest-even
    return (unsigned short)(u >> 16);
}
__device__ __forceinline__ float bflo(unsigned u) {
    return __builtin_bit_cast(float, u << 16);
}
__device__ __forceinline__ float bfhi(unsigned u) {
    return __builtin_bit_cast(float, u & 0xFFFF0000u);
}
__device__ __forceinline__ unsigned cvtpk2(float a, float b) {
    unsigned r;
    asm("v_cvt_pk_bf16_f32 %0, %1, %2" : "=v"(r) : "v"(a), "v"(b));
    return r;   // low16 = bf16(a), high16 = bf16(b)
}
__device__ __forceinline__ void gload_lds16(const void* g, void* l) {
    __builtin_amdgcn_global_load_lds((const __attribute__((address_space(1))) void*)g,
                                     (__attribute__((address_space(3))) void*)l, 16, 0, 0);
}

// ---------------------------------------------------------------------------
// CSR build: histogram -> hierarchical scan -> scatter (packed int2 metadata)
// ---------------------------------------------------------------------------

__global__ void count_kernel(const int* __restrict__ dst, int* __restrict__ counts, int E) {
    int i = blockIdx.x * blockDim.x + threadIdx.x;
    if (i < E) atomicAdd(&counts[dst[i]], 1);
}

__global__ __launch_bounds__(256) void scan_p1(const int* __restrict__ counts,
                                               int* __restrict__ partial, int n) {
    __shared__ int ws[4];
    int b = blockIdx.x, t = threadIdx.x;
    int base = b * 1024 + t * 4;
    int s = 0;
#pragma unroll
    for (int j = 0; j < 4; ++j) {
        int idx = base + j;
        if (idx < n) s += counts[idx];
    }
#pragma unroll
    for (int off = 32; off; off >>= 1) s += __shfl_xor(s, off, 64);
    if ((t & 63) == 0) ws[t >> 6] = s;
    __syncthreads();
    if (t == 0) partial[b] = ws[0] + ws[1] + ws[2] + ws[3];
}

__global__ __launch_bounds__(128) void scan_p2(int* __restrict__ partial, int nb) {
    __shared__ int s[128];
    int t = threadIdx.x;
    int v = (t < nb) ? partial[t] : 0;
    s[t] = v;
    __syncthreads();
    for (int off = 1; off < 128; off <<= 1) {
        int u = (t >= off) ? s[t - off] : 0;
        __syncthreads();
        s[t] += u;
        __syncthreads();
    }
    if (t < nb) partial[t] = (t == 0) ? 0 : s[t - 1];
}

__global__ __launch_bounds__(256) void scan_p3(const int* __restrict__ counts,
                                               const int* __restrict__ partial,
                                               int* __restrict__ row_ptr,
                                               int* __restrict__ fill, int n) {
    __shared__ int ts[256];
    int b = blockIdx.x, t = threadIdx.x;
    int base = b * 1024 + t * 4;
    int c[4];
#pragma unroll
    for (int j = 0; j < 4; ++j) {
        int idx = base + j;
        c[j] = (idx < n) ? counts[idx] : 0;
    }
    int s = c[0] + c[1] + c[2] + c[3];
    ts[t] = s;
    __syncthreads();
    for (int off = 1; off < 256; off <<= 1) {
        int v = (t >= off) ? ts[t - off] : 0;
        __syncthreads();
        ts[t] += v;
        __syncthreads();
    }
    int pre = partial[b] + ((t == 0) ? 0 : ts[t - 1]);
#pragma unroll
    for (int j = 0; j < 4; ++j) {
        int idx = base + j;
        if (idx < n) {
            row_ptr[idx] = pre;
            fill[idx] = pre;
            if (idx == n - 1) row_ptr[n] = pre + c[j];
            pre += c[j];
        }
    }
}

__global__ void scatter_kernel(const int* __restrict__ src, const int* __restrict__ dst,
                               const float* __restrict__ w, int* __restrict__ fill,
                               int2* __restrict__ epk, int E) {
    int i = blockIdx.x * blockDim.x + threadIdx.x;
    if (i < E) {
        int d = dst[i];
        int pos = atomicAdd(&fill[d], 1);
        int2 m; m.x = src[i]; m.y = __builtin_bit_cast(int, w[i]);
        epk[pos] = m;
    }
}

// ---------------------------------------------------------------------------
// Weight transpose + bf16 convert: Wt[n][k] = bf16(W[k][n])
// ---------------------------------------------------------------------------
__global__ void wtrans_kernel(const float* __restrict__ W, unsigned short* __restrict__ Wt,
                              int K, int N) {
    int idx = blockIdx.x * blockDim.x + threadIdx.x;
    if (idx >= N * K) return;
    int n = idx / K, k = idx - n * K;
    Wt[idx] = f2bf(W[(size_t)k * N + n]);
}

// ---------------------------------------------------------------------------
// GEMM layer 1, m97-style: small LDS, single buffer, high block residency.
// Hb[M][256] = relu(X[M][512] @ W1t[256][512]^T + b1)
// Tile 128x128, grid (2 cols, rows), 256 threads (4 waves 2x2), BK=32.
// LDS 24KB (A f32 16KB two k-half planes + B bf16 8KB) -> ~6 blocks/CU.
// Loop: stage -> vmcnt(0)+sync -> frag-read+cvt+16 MFMA -> sync.
// Inter-block TLP hides the per-step drain (m97 regime).
// ---------------------------------------------------------------------------
__global__ __launch_bounds__(256) void gemm1_m97(const float* __restrict__ X,
                                                 const unsigned short* __restrict__ W1t,
                                                 const float* __restrict__ b1,
                                                 unsigned short* __restrict__ Hb, int M) {
    __shared__ char smem[24576];           // A 16KB (2 planes of 8KB) + B 8KB
    char* const Abuf = smem;
    char* const Bbuf = smem + 16384;

    const int tid = threadIdx.x;
    const int lane = tid & 63;
    const int wv = tid >> 6;               // 0..3
    const int wr = wv >> 1, wc = wv & 1;
    const int bcol = blockIdx.x * 128;     // 0 or 128
    const int brow = blockIdx.y * 128;

    // A chunks: ci = wv + c*4, c=0..3.  ci<8: plane0 sub=ci, k+=0; ci>=8: plane1 sub=ci-8, k+=4
    const char* asrc[4];
    int adst[4];
#pragma unroll
    for (int c = 0; c < 4; ++c) {
        int ci = wv + c * 4;
        int sub = ci & 7, plane = ci >> 3;
        int ar = brow + sub * 16 + (lane & 15); if (ar > M - 1) ar = M - 1;
        asrc[c] = (const char*)&X[(size_t)ar * NFEAT + (lane >> 4) * 8 + plane * 4];
        adst[c] = ci * 1024;
    }
    // B chunks: ci = wv + c*4, c=0..1: col = bcol + ci*16 + (lane&15), k = (lane>>4)*8
    const char* bsrc[2];
    int bdst[2];
#pragma unroll
    for (int c = 0; c < 2; ++c) {
        int ci = wv + c * 4;
        int col = bcol + ci * 16 + (lane & 15);
        bsrc[c] = (const char*)&W1t[(size_t)col * NFEAT + (lane >> 4) * 8];
        bdst[c] = ci * 1024;
    }

    f32x4 acc[4][4];
#pragma unroll
    for (int m = 0; m < 4; ++m)
#pragma unroll
        for (int n = 0; n < 4; ++n) acc[m][n] = f32x4{0.f, 0.f, 0.f, 0.f};

    for (int s = 0; s < NFEAT / 32; ++s) {
#pragma unroll
        for (int c = 0; c < 4; ++c)
            gload_lds16(asrc[c] + (size_t)s * 128, Abuf + adst[c]);
#pragma unroll
        for (int c = 0; c < 2; ++c)
            gload_lds16(bsrc[c] + (size_t)s * 64, Bbuf + bdst[c]);
        asm volatile("s_waitcnt vmcnt(0)" ::: "memory");
        __syncthreads();

        short8v a[4], b[4];
#pragma unroll
        for (int m = 0; m < 4; ++m) {
            int g = ((wr * 4 + m) * 64 + lane) * 16;
            f32x4 lo = *(const f32x4*)(Abuf + g);
            f32x4 hi = *(const f32x4*)(Abuf + 8192 + g);
            uint4 u;
            u.x = cvtpk2(lo[0], lo[1]); u.y = cvtpk2(lo[2], lo[3]);
            u.z = cvtpk2(hi[0], hi[1]); u.w = cvtpk2(hi[2], hi[3]);
            a[m] = __builtin_bit_cast(short8v, u);
        }
#pragma unroll
        for (int n = 0; n < 4; ++n)
            b[n] = *(const short8v*)(Bbuf + ((wc * 4 + n) * 64 + lane) * 16);
#pragma unroll
        for (int m = 0; m < 4; ++m)
#pragma unroll
            for (int n = 0; n < 4; ++n)
                acc[m][n] = __builtin_amdgcn_mfma_f32_16x16x32_bf16(a[m], b[n], acc[m][n], 0, 0, 0);
        __syncthreads();
    }

#pragma unroll
    for (int n = 0; n < 4; ++n) {
        int colg = bcol + wc * 64 + n * 16 + (lane & 15);
        float bv = b1[colg];
#pragma unroll
        for (int m = 0; m < 4; ++m) {
#pragma unroll
            for (int r = 0; r < 4; ++r) {
                int rowg = brow + wr * 64 + m * 16 + (lane >> 4) * 4 + r;
                if (rowg < M) {
                    float v = fmaxf(acc[m][n][r] + bv, 0.f);
                    Hb[(size_t)rowg * NHID + colg] = f2bf(v);
                }
            }
        }
    }
}

// ---------------------------------------------------------------------------
// GEMM layer 2, m97-style: C0[M][128] = Hb[M][256] @ W2t[128][256]^T + b2
// Tile 128x128, grid (782), 256 threads, BK=32, LDS 16KB single buffer.
// ---------------------------------------------------------------------------
__global__ __launch_bounds__(256) void gemm2_m97(const unsigned short* __restrict__ Hb,
                                                 const unsigned short* __restrict__ W2t,
                                                 const float* __restrict__ b2,
                                                 unsigned short* __restrict__ C0, int M) {
    __shared__ char smem[16384];           // A 8KB + B 8KB
    char* const Abuf = smem;
    char* const Bbuf = smem + 8192;

    const int tid = threadIdx.x;
    const int lane = tid & 63;
    const int wv = tid >> 6;               // 0..3
    const int wr = wv >> 1, wc = wv & 1;
    const int brow = blockIdx.x * 128;

    const char* asrc[2];
    const char* bsrc[2];
    int cdst[2];
#pragma unroll
    for (int c = 0; c < 2; ++c) {
        int ci = wv + c * 4;               // 0..7
        int ar = brow + ci * 16 + (lane & 15); if (ar > M - 1) ar = M - 1;
        asrc[c] = (const char*)&Hb[(size_t)ar * NHID + (lane >> 4) * 8];
        int col = ci * 16 + (lane & 15);
        bsrc[c] = (const char*)&W2t[(size_t)col * NHID + (lane >> 4) * 8];
        cdst[c] = ci * 1024;
    }

    f32x4 acc[4][4];
#pragma unroll
    for (int m = 0; m < 4; ++m)
#pragma unroll
        for (int n = 0; n < 4; ++n) acc[m][n] = f32x4{0.f, 0.f, 0.f, 0.f};

    for (int s = 0; s < NHID / 32; ++s) {
#pragma unroll
        for (int c = 0; c < 2; ++c) {
            gload_lds16(asrc[c] + (size_t)s * 64, Abuf + cdst[c]);
            gload_lds16(bsrc[c] + (size_t)s * 64, Bbuf + cdst[c]);
        }
        asm volatile("s_waitcnt vmcnt(0)" ::: "memory");
        __syncthreads();

        short8v a[4], b[4];
#pragma unroll
        for (int m = 0; m < 4; ++m)
            a[m] = *(const short8v*)(Abuf + ((wr * 4 + m) * 64 + lane) * 16);
#pragma unroll
        for (int n = 0; n < 4; ++n)
            b[n] = *(const short8v*)(Bbuf + ((wc * 4 + n) * 64 + lane) * 16);
#pragma unroll
        for (int m = 0; m < 4; ++m)
#pragma unroll
            for (int n = 0; n < 4; ++n)
                acc[m][n] = __builtin_amdgcn_mfma_f32_16x16x32_bf16(a[m], b[n], acc[m][n], 0, 0, 0);
        __syncthreads();
    }

#pragma unroll
    for (int n = 0; n < 4; ++n) {
        int colg = wc * 64 + n * 16 + (lane & 15);
        float bv = b2[colg];
#pragma unroll
        for (int m = 0; m < 4; ++m) {
#pragma unroll
            for (int r = 0; r < 4; ++r) {
                int rowg = brow + wr * 64 + m * 16 + (lane >> 4) * 4 + r;
                if (rowg < M)
                    C0[(size_t)rowg * NCLASS + colg] = f2bf(acc[m][n][r] + bv);
            }
        }
    }
}

// ---------------------------------------------------------------------------
// One propagation hop (pull over CSR-by-dst), bf16 carry, packed int2 edges.
// (R5 structure — 88us/hop.) One wave per node; lanes preload up to 64 edges'
// metadata (one 8B load), broadcast via readlane. Unroll 8 for MLP.
// FINAL=1: fuse log-softmax, write f32 to outf.
// ---------------------------------------------------------------------------
template<int FINAL>
__global__ __launch_bounds__(256) void hop_kernel(const unsigned short* __restrict__ carry,
                                                  const unsigned short* __restrict__ c0,
                                                  const int* __restrict__ rp,
                                                  const int2* __restrict__ epk,
                                                  unsigned short* __restrict__ outb,
                                                  float* __restrict__ outf, int nnodes) {
    int node = blockIdx.x * 4 + (threadIdx.x >> 6);
    if (node >= nnodes) return;
    int lane = threadIdx.x & 63;
    int e0 = rp[node], e1 = rp[node + 1];

    float a0x = 0.f, a0y = 0.f, a1x = 0.f, a1y = 0.f;
    float a2x = 0.f, a2y = 0.f, a3x = 0.f, a3y = 0.f;

    for (int eb = e0; eb < e1; eb += 64) {
        int nb = e1 - eb; if (nb > 64) nb = 64;
        int cs = 0, wvi = 0;
        if (lane < nb) {
            int2 m = epk[eb + lane];
            cs = m.x; wvi = m.y;
        }
        int j = 0;
        for (; j + 7 < nb; j += 8) {
            int s0 = __builtin_amdgcn_readlane(cs, j);
            int s1 = __builtin_amdgcn_readlane(cs, j + 1);
            int s2 = __builtin_amdgcn_readlane(cs, j + 2);
            int s3 = __builtin_amdgcn_readlane(cs, j + 3);
            int s4 = __builtin_amdgcn_readlane(cs, j + 4);
            int s5 = __builtin_amdgcn_readlane(cs, j + 5);
            int s6 = __builtin_amdgcn_readlane(cs, j + 6);
            int s7 = __builtin_amdgcn_readlane(cs, j + 7);
            float w0 = __builtin_bit_cast(float, __builtin_amdgcn_readlane(wvi, j));
            float w1 = __builtin_bit_cast(float, __builtin_amdgcn_readlane(wvi, j + 1));
            float w2 = __builtin_bit_cast(float, __builtin_amdgcn_readlane(wvi, j + 2));
            float w3 = __builtin_bit_cast(float, __builtin_amdgcn_readlane(wvi, j + 3));
            float w4 = __builtin_bit_cast(float, __builtin_amdgcn_readlane(wvi, j + 4));
            float w5 = __builtin_bit_cast(float, __builtin_amdgcn_readlane(wvi, j + 5));
            float w6 = __builtin_bit_cast(float, __builtin_amdgcn_readlane(wvi, j + 6));
            float w7 = __builtin_bit_cast(float, __builtin_amdgcn_readlane(wvi, j + 7));
            unsigned u0 = ((const unsigned*)(carry + ((size_t)s0 << 7)))[lane];
            unsigned u1 = ((const unsigned*)(carry + ((size_t)s1 << 7)))[lane];
            unsigned u2 = ((const unsigned*)(carry + ((size_t)s2 << 7)))[lane];
            unsigned u3 = ((const unsigned*)(carry + ((size_t)s3 << 7)))[lane];
            unsigned u4 = ((const unsigned*)(carry + ((size_t)s4 << 7)))[lane];
            unsigned u5 = ((const unsigned*)(carry + ((size_t)s5 << 7)))[lane];
            unsigned u6 = ((const unsigned*)(carry + ((size_t)s6 << 7)))[lane];
            unsigned u7 = ((const unsigned*)(carry + ((size_t)s7 << 7)))[lane];
            a0x = fmaf(w0, bflo(u0), a0x); a0y = fmaf(w0, bfhi(u0), a0y);
            a1x = fmaf(w1, bflo(u1), a1x); a1y = fmaf(w1, bfhi(u1), a1y);
            a2x = fmaf(w2, bflo(u2), a2x); a2y = fmaf(w2, bfhi(u2), a2y);
            a3x = fmaf(w3, bflo(u3), a3x); a3y = fmaf(w3, bfhi(u3), a3y);
            a0x = fmaf(w4, bflo(u4), a0x); a0y = fmaf(w4, bfhi(u4), a0y);
            a1x = fmaf(w5, bflo(u5), a1x); a1y = fmaf(w5, bfhi(u5), a1y);
            a2x = fmaf(w6, bflo(u6), a2x); a2y = fmaf(w6, bfhi(u6), a2y);
            a3x = fmaf(w7, bflo(u7), a3x); a3y = fmaf(w7, bfhi(u7), a3y);
        }
        for (; j + 3 < nb; j += 4) {
            int s0 = __builtin_amdgcn_readlane(cs, j);
            int s1 = __builtin_amdgcn_readlane(cs, j + 1);
            int s2 = __builtin_amdgcn_readlane(cs, j + 2);
            int s3 = __builtin_amdgcn_readlane(cs, j + 3);
            float w0 = __builtin_bit_cast(float, __builtin_amdgcn_readlane(wvi, j));
            float w1 = __builtin_bit_cast(float, __builtin_amdgcn_readlane(wvi, j + 1));
            float w2 = __builtin_bit_cast(float, __builtin_amdgcn_readlane(wvi, j + 2));
            float w3 = __builtin_bit_cast(float, __builtin_amdgcn_readlane(wvi, j + 3));
            unsigned u0 = ((const unsigned*)(carry + ((size_t)s0 << 7)))[lane];
            unsigned u1 = ((const unsigned*)(carry + ((size_t)s1 << 7)))[lane];
            unsigned u2 = ((const unsigned*)(carry + ((size_t)s2 << 7)))[lane];
            unsigned u3 = ((const unsigned*)(carry + ((size_t)s3 << 7)))[lane];
            a0x = fmaf(w0, bflo(u0), a0x); a0y = fmaf(w0, bfhi(u0), a0y);
            a1x = fmaf(w1, bflo(u1), a1x); a1y = fmaf(w1, bfhi(u1), a1y);
            a2x = fmaf(w2, bflo(u2), a2x); a2y = fmaf(w2, bfhi(u2), a2y);
            a3x = fmaf(w3, bflo(u3), a3x); a3y = fmaf(w3, bfhi(u3), a3y);
        }
        for (; j < nb; ++j) {
            int s0 = __builtin_amdgcn_readlane(cs, j);
            float w0 = __builtin_bit_cast(float, __builtin_amdgcn_readlane(wvi, j));
            unsigned u0 = ((const unsigned*)(carry + ((size_t)s0 << 7)))[lane];
            a0x = fmaf(w0, bflo(u0), a0x); a0y = fmaf(w0, bfhi(u0), a0y);
        }
    }

    unsigned ux = ((const unsigned*)(c0 + ((size_t)node << 7)))[lane];
    float vx = (1.f - ALPHA) * (a0x + a1x + a2x + a3x) + ALPHA * bflo(ux);
    float vy = (1.f - ALPHA) * (a0y + a1y + a2y + a3y) + ALPHA * bfhi(ux);

    if (FINAL) {
        float mx = fmaxf(vx, vy);
#pragma unroll
        for (int off = 32; off; off >>= 1) mx = fmaxf(mx, __shfl_xor(mx, off, 64));
        float se = __expf(vx - mx) + __expf(vy - mx);
#pragma unroll
        for (int off = 32; off; off >>= 1) se += __shfl_xor(se, off, 64);
        float l = mx + __logf(se);
        float2 o; o.x = vx - l; o.y = vy - l;
        ((float2*)(outf + ((size_t)node << 7)))[lane] = o;
    } else {
        unsigned o = (unsigned)f2bf(vx) | ((unsigned)f2bf(vy) << 16);
        ((unsigned*)(outb + ((size_t)node << 7)))[lane] = o;
    }
}

// ---------------------------------------------------------------------------

extern "C" void kernel_launch(void* const* d_in, const int* in_sizes, int n_in,
                              void* d_out, int out_size, void* d_ws, size_t ws_size,
                              hipStream_t stream) {
    const float* x   = (const float*)d_in[0];
    const int*   ei  = (const int*)d_in[1];
    const float* ew  = (const float*)d_in[2];
    const float* W1  = (const float*)d_in[3];
    const float* b1  = (const float*)d_in[4];
    const float* W2  = (const float*)d_in[5];
    const float* b2  = (const float*)d_in[6];
    float* outp = (float*)d_out;

    const int E = in_sizes[1] / 2;
    const int Nn = N_NODES;
    const int* srcv = ei;
    const int* dstv = ei + E;
    const size_t NC = (size_t)Nn * NCLASS;   // 12.8M elements

    // workspace layout (16B-aligned buffers)
    unsigned short* c0  = (unsigned short*)d_ws;    // bf16 x0 copy     [NC]
    unsigned short* A16 = c0 + NC;                  // ping             [NC]
    unsigned short* B16 = A16 + NC;                 // pong             [NC]
    unsigned short* hb  = A16;                      // H bf16 overlay (dead before hops)
    unsigned short* w1t = B16 + NC;                 // 256x512
    unsigned short* w2t = w1t + NHID * NFEAT;       // 128x256
    int* row_ptr = (int*)(w2t + NCLASS * NHID);     // Nn+1
    int* fill    = row_ptr + (Nn + 1);              // Nn (counts)
    int* partial = fill + Nn;                       // 128
    int2* epk    = (int2*)(partial + 128);          // E packed {src, w}

    const int NB = (Nn + 1023) / 1024;              // 98 scan blocks

    // ---- CSR build ----
    hipMemsetAsync(fill, 0, (size_t)Nn * sizeof(int), stream);
    count_kernel<<<(E + 255) / 256, 256, 0, stream>>>(dstv, fill, E);
    scan_p1<<<NB, 256, 0, stream>>>(fill, partial, Nn);
    scan_p2<<<1, 128, 0, stream>>>(partial, NB);
    scan_p3<<<NB, 256, 0, stream>>>(fill, partial, row_ptr, fill, Nn);
    scatter_kernel<<<(E + 255) / 256, 256, 0, stream>>>(srcv, dstv, ew, fill, epk, E);

    // ---- weight prep ----
    wtrans_kernel<<<(NHID * NFEAT + 255) / 256, 256, 0, stream>>>(W1, w1t, NFEAT, NHID);
    wtrans_kernel<<<(NCLASS * NHID + 255) / 256, 256, 0, stream>>>(W2, w2t, NHID, NCLASS);

    // ---- MLP (bf16 MFMA, m97-style small-LDS high-residency) ----
    {
        dim3 g1(2, (Nn + 127) / 128);               // cols fastest: X row shared via L2
        gemm1_m97<<<g1, 256, 0, stream>>>(x, w1t, b1, hb, Nn);
        gemm2_m97<<<(Nn + 127) / 128, 256, 0, stream>>>(hb, w2t, b2, c0, Nn);
    }

    // ---- K_HOPS propagation (bf16 carry), ping-pong; last hop fuses softmax ----
    int grid = (Nn + 3) / 4;
    const unsigned short* carry = c0;
    unsigned short* dsts[2] = {A16, B16};
    for (int k = 0; k < K_HOPS - 1; ++k) {
        unsigned short* o = dsts[k & 1];
        hop_kernel<0><<<grid, 256, 0, stream>>>(carry, c0, row_ptr, epk, o, nullptr, Nn);
        carry = o;
    }
    hop_kernel<1><<<grid, 256, 0, stream>>>(carry, c0, row_ptr, epk, nullptr, outp, Nn);
}

// Round 10
// 645.152 us; speedup vs baseline: 1.0711x; 1.0711x over previous
//
#include <hip/hip_runtime.h>
#include <hip/hip_bf16.h>
#include <cstdint>
#include <cstddef>

#define N_NODES 100000
#define NFEAT 512
#define NHID 256
#define NCLASS 128
#define K_HOPS 5
#define ALPHA 0.1f

typedef __attribute__((ext_vector_type(8))) short short8v;   // 8 bf16 (4 VGPRs)
typedef __attribute__((ext_vector_type(4))) float f32x4;     // MFMA accumulator

__device__ __forceinline__ unsigned short f2bf(float f) {
    unsigned u = __builtin_bit_cast(unsigned, f);
    u += 0x7FFFu + ((u >> 16) & 1u);      // round-to-nearest-even
    return (unsigned short)(u >> 16);
}
__device__ __forceinline__ float bflo(unsigned u) {
    return __builtin_bit_cast(float, u << 16);
}
__device__ __forceinline__ float bfhi(unsigned u) {
    return __builtin_bit_cast(float, u & 0xFFFF0000u);
}
__device__ __forceinline__ unsigned cvtpk2(float a, float b) {
    unsigned r;
    asm("v_cvt_pk_bf16_f32 %0, %1, %2" : "=v"(r) : "v"(a), "v"(b));
    return r;   // low16 = bf16(a), high16 = bf16(b)
}
__device__ __forceinline__ void gload_lds16(const void* g, void* l) {
    __builtin_amdgcn_global_load_lds((const __attribute__((address_space(1))) void*)g,
                                     (__attribute__((address_space(3))) void*)l, 16, 0, 0);
}

// ---------------------------------------------------------------------------
// CSR build: histogram -> hierarchical scan -> scatter (packed int2 metadata)
// ---------------------------------------------------------------------------

__global__ void count_kernel(const int* __restrict__ dst, int* __restrict__ counts, int E) {
    int i = blockIdx.x * blockDim.x + threadIdx.x;
    if (i < E) atomicAdd(&counts[dst[i]], 1);
}

__global__ __launch_bounds__(256) void scan_p1(const int* __restrict__ counts,
                                               int* __restrict__ partial, int n) {
    __shared__ int ws[4];
    int b = blockIdx.x, t = threadIdx.x;
    int base = b * 1024 + t * 4;
    int s = 0;
#pragma unroll
    for (int j = 0; j < 4; ++j) {
        int idx = base + j;
        if (idx < n) s += counts[idx];
    }
#pragma unroll
    for (int off = 32; off; off >>= 1) s += __shfl_xor(s, off, 64);
    if ((t & 63) == 0) ws[t >> 6] = s;
    __syncthreads();
    if (t == 0) partial[b] = ws[0] + ws[1] + ws[2] + ws[3];
}

__global__ __launch_bounds__(128) void scan_p2(int* __restrict__ partial, int nb) {
    __shared__ int s[128];
    int t = threadIdx.x;
    int v = (t < nb) ? partial[t] : 0;
    s[t] = v;
    __syncthreads();
    for (int off = 1; off < 128; off <<= 1) {
        int u = (t >= off) ? s[t - off] : 0;
        __syncthreads();
        s[t] += u;
        __syncthreads();
    }
    if (t < nb) partial[t] = (t == 0) ? 0 : s[t - 1];
}

__global__ __launch_bounds__(256) void scan_p3(const int* __restrict__ counts,
                                               const int* __restrict__ partial,
                                               int* __restrict__ row_ptr,
                                               int* __restrict__ fill, int n) {
    __shared__ int ts[256];
    int b = blockIdx.x, t = threadIdx.x;
    int base = b * 1024 + t * 4;
    int c[4];
#pragma unroll
    for (int j = 0; j < 4; ++j) {
        int idx = base + j;
        c[j] = (idx < n) ? counts[idx] : 0;
    }
    int s = c[0] + c[1] + c[2] + c[3];
    ts[t] = s;
    __syncthreads();
    for (int off = 1; off < 256; off <<= 1) {
        int v = (t >= off) ? ts[t - off] : 0;
        __syncthreads();
        ts[t] += v;
        __syncthreads();
    }
    int pre = partial[b] + ((t == 0) ? 0 : ts[t - 1]);
#pragma unroll
    for (int j = 0; j < 4; ++j) {
        int idx = base + j;
        if (idx < n) {
            row_ptr[idx] = pre;
            fill[idx] = pre;
            if (idx == n - 1) row_ptr[n] = pre + c[j];
            pre += c[j];
        }
    }
}

__global__ void scatter_kernel(const int* __restrict__ src, const int* __restrict__ dst,
                               const float* __restrict__ w, int* __restrict__ fill,
                               int2* __restrict__ epk, int E) {
    int i = blockIdx.x * blockDim.x + threadIdx.x;
    if (i < E) {
        int d = dst[i];
        int pos = atomicAdd(&fill[d], 1);
        int2 m; m.x = src[i]; m.y = __builtin_bit_cast(int, w[i]);
        epk[pos] = m;
    }
}

// ---------------------------------------------------------------------------
// Weight transpose + bf16 convert: Wt[n][k] = bf16(W[k][n])
// ---------------------------------------------------------------------------
__global__ void wtrans_kernel(const float* __restrict__ W, unsigned short* __restrict__ Wt,
                              int K, int N) {
    int idx = blockIdx.x * blockDim.x + threadIdx.x;
    if (idx >= N * K) return;
    int n = idx / K, k = idx - n * K;
    Wt[idx] = f2bf(W[(size_t)k * N + n]);
}

// ---------------------------------------------------------------------------
// GEMM layer 1, contiguous-row A staging + XOR-swizzled LDS.
// Hb[M][256] = relu(X[M][512] @ W1t[256][512]^T + b1)
// Tile 128x256 (full N, X read once), 512 threads (8 waves 2x4), BK=32.
// A LDS: row-major [128][128B] f32, swizzle byte^=(row&7)<<4. Staging:
// each gload_lds covers 8 rows x 128B CONTIGUOUS global (pre-swizzled
// per-lane source; LDS dest linear) — 16 full 64B lines/instr vs the
// frag-major layout's 32 half-lines (the invariant across all prior
// ~140us variants). Frag read = 2x ds_read_b128, 2-way banks (free).
// B: frag-major (source is L2-resident w1t — pattern irrelevant).
// ---------------------------------------------------------------------------
__global__ __launch_bounds__(512) void gemm1_cont(const float* __restrict__ X,
                                                  const unsigned short* __restrict__ W1t,
                                                  const float* __restrict__ b1,
                                                  unsigned short* __restrict__ Hb, int M) {
    __shared__ char smem[32768];
    char* const Abuf = smem;           // 16KB: [128 rows][128B] swizzled f32
    char* const Bbuf = smem + 16384;   // 16KB: frag-major bf16, 256 cols

    const int tid = threadIdx.x;
    const int lane = tid & 63;
    const int wv = tid >> 6;           // 0..7
    const int wr = wv >> 2, wc = wv & 3;
    const int brow = blockIdx.x * 128;

    // A staging: chunk c: row = c*64 + wv*8 + (lane>>3)  (so row&7 == lane>>3)
    // LDS slot = row*128 + (lane&7)*16 (linear); it holds element byte
    // kb = ((lane&7)*16) ^ ((row&7)<<4)  -> fetch that byte from global.
    const char* asrc[2];
    int adst[2];
#pragma unroll
    for (int c = 0; c < 2; ++c) {
        int row = c * 64 + wv * 8 + (lane >> 3);
        int ar = brow + row; if (ar > M - 1) ar = M - 1;
        int kb = ((lane & 7) << 4) ^ ((lane >> 3) << 4);
        asrc[c] = (const char*)X + (size_t)ar * (NFEAT * 4) + kb;
        adst[c] = c * 8192 + wv * 1024;
    }
    // B staging: frag-major chunks ci = wv + c*8
    const char* bsrc[2];
    int bdst[2];
#pragma unroll
    for (int c = 0; c < 2; ++c) {
        int ci = wv + c * 8;
        int col = ci * 16 + (lane & 15);
        bsrc[c] = (const char*)&W1t[(size_t)col * NFEAT + (lane >> 4) * 8];
        bdst[c] = ci * 1024;
    }

    f32x4 acc[4][4];
#pragma unroll
    for (int m = 0; m < 4; ++m)
#pragma unroll
        for (int n = 0; n < 4; ++n) acc[m][n] = f32x4{0.f, 0.f, 0.f, 0.f};

    for (int s = 0; s < NFEAT / 32; ++s) {
#pragma unroll
        for (int c = 0; c < 2; ++c)
            gload_lds16(asrc[c] + (size_t)s * 128, Abuf + adst[c]);
#pragma unroll
        for (int c = 0; c < 2; ++c)
            gload_lds16(bsrc[c] + (size_t)s * 64, Bbuf + bdst[c]);
        asm volatile("s_waitcnt vmcnt(0)" ::: "memory");
        __syncthreads();

        short8v a[4], b[4];
#pragma unroll
        for (int m = 0; m < 4; ++m) {
            int row = wr * 64 + m * 16 + (lane & 15);
            int s4 = (row & 7) << 4;
            int kb = (lane >> 4) * 32;
            f32x4 lo = *(const f32x4*)(Abuf + row * 128 + ((kb + 0) ^ s4));
            f32x4 hi = *(const f32x4*)(Abuf + row * 128 + ((kb + 16) ^ s4));
            uint4 u;
            u.x = cvtpk2(lo[0], lo[1]); u.y = cvtpk2(lo[2], lo[3]);
            u.z = cvtpk2(hi[0], hi[1]); u.w = cvtpk2(hi[2], hi[3]);
            a[m] = __builtin_bit_cast(short8v, u);
        }
#pragma unroll
        for (int n = 0; n < 4; ++n)
            b[n] = *(const short8v*)(Bbuf + ((wc * 4 + n) * 64 + lane) * 16);
#pragma unroll
        for (int m = 0; m < 4; ++m)
#pragma unroll
            for (int n = 0; n < 4; ++n)
                acc[m][n] = __builtin_amdgcn_mfma_f32_16x16x32_bf16(a[m], b[n], acc[m][n], 0, 0, 0);
        __syncthreads();
    }

#pragma unroll
    for (int n = 0; n < 4; ++n) {
        int colg = wc * 64 + n * 16 + (lane & 15);
        float bv = b1[colg];
#pragma unroll
        for (int m = 0; m < 4; ++m) {
#pragma unroll
            for (int r = 0; r < 4; ++r) {
                int rowg = brow + wr * 64 + m * 16 + (lane >> 4) * 4 + r;
                if (rowg < M) {
                    float v = fmaxf(acc[m][n][r] + bv, 0.f);
                    Hb[(size_t)rowg * NHID + colg] = f2bf(v);
                }
            }
        }
    }
}

// ---------------------------------------------------------------------------
// GEMM layer 2 (unchanged, ~25us): C0[M][128] = Hb[M][256] @ W2t^T + b2
// ---------------------------------------------------------------------------
__global__ __launch_bounds__(256) void gemm2_m97(const unsigned short* __restrict__ Hb,
                                                 const unsigned short* __restrict__ W2t,
                                                 const float* __restrict__ b2,
                                                 unsigned short* __restrict__ C0, int M) {
    __shared__ char smem[16384];           // A 8KB + B 8KB
    char* const Abuf = smem;
    char* const Bbuf = smem + 8192;

    const int tid = threadIdx.x;
    const int lane = tid & 63;
    const int wv = tid >> 6;               // 0..3
    const int wr = wv >> 1, wc = wv & 1;
    const int brow = blockIdx.x * 128;

    const char* asrc[2];
    const char* bsrc[2];
    int cdst[2];
#pragma unroll
    for (int c = 0; c < 2; ++c) {
        int ci = wv + c * 4;               // 0..7
        int ar = brow + ci * 16 + (lane & 15); if (ar > M - 1) ar = M - 1;
        asrc[c] = (const char*)&Hb[(size_t)ar * NHID + (lane >> 4) * 8];
        int col = ci * 16 + (lane & 15);
        bsrc[c] = (const char*)&W2t[(size_t)col * NHID + (lane >> 4) * 8];
        cdst[c] = ci * 1024;
    }

    f32x4 acc[4][4];
#pragma unroll
    for (int m = 0; m < 4; ++m)
#pragma unroll
        for (int n = 0; n < 4; ++n) acc[m][n] = f32x4{0.f, 0.f, 0.f, 0.f};

    for (int s = 0; s < NHID / 32; ++s) {
#pragma unroll
        for (int c = 0; c < 2; ++c) {
            gload_lds16(asrc[c] + (size_t)s * 64, Abuf + cdst[c]);
            gload_lds16(bsrc[c] + (size_t)s * 64, Bbuf + cdst[c]);
        }
        asm volatile("s_waitcnt vmcnt(0)" ::: "memory");
        __syncthreads();

        short8v a[4], b[4];
#pragma unroll
        for (int m = 0; m < 4; ++m)
            a[m] = *(const short8v*)(Abuf + ((wr * 4 + m) * 64 + lane) * 16);
#pragma unroll
        for (int n = 0; n < 4; ++n)
            b[n] = *(const short8v*)(Bbuf + ((wc * 4 + n) * 64 + lane) * 16);
#pragma unroll
        for (int m = 0; m < 4; ++m)
#pragma unroll
            for (int n = 0; n < 4; ++n)
                acc[m][n] = __builtin_amdgcn_mfma_f32_16x16x32_bf16(a[m], b[n], acc[m][n], 0, 0, 0);
        __syncthreads();
    }

#pragma unroll
    for (int n = 0; n < 4; ++n) {
        int colg = wc * 64 + n * 16 + (lane & 15);
        float bv = b2[colg];
#pragma unroll
        for (int m = 0; m < 4; ++m) {
#pragma unroll
            for (int r = 0; r < 4; ++r) {
                int rowg = brow + wr * 64 + m * 16 + (lane >> 4) * 4 + r;
                if (rowg < M)
                    C0[(size_t)rowg * NCLASS + colg] = f2bf(acc[m][n][r] + bv);
            }
        }
    }
}

// ---------------------------------------------------------------------------
// One propagation hop (pull over CSR-by-dst), bf16 carry, packed int2 edges.
// (R5 structure — 88us/hop.) One wave per node; lanes preload up to 64 edges'
// metadata (one 8B load), broadcast via readlane. Unroll 8 for MLP.
// FINAL=1: fuse log-softmax, write f32 to outf.
// ---------------------------------------------------------------------------
template<int FINAL>
__global__ __launch_bounds__(256) void hop_kernel(const unsigned short* __restrict__ carry,
                                                  const unsigned short* __restrict__ c0,
                                                  const int* __restrict__ rp,
                                                  const int2* __restrict__ epk,
                                                  unsigned short* __restrict__ outb,
                                                  float* __restrict__ outf, int nnodes) {
    int node = blockIdx.x * 4 + (threadIdx.x >> 6);
    if (node >= nnodes) return;
    int lane = threadIdx.x & 63;
    int e0 = rp[node], e1 = rp[node + 1];

    float a0x = 0.f, a0y = 0.f, a1x = 0.f, a1y = 0.f;
    float a2x = 0.f, a2y = 0.f, a3x = 0.f, a3y = 0.f;

    for (int eb = e0; eb < e1; eb += 64) {
        int nb = e1 - eb; if (nb > 64) nb = 64;
        int cs = 0, wvi = 0;
        if (lane < nb) {
            int2 m = epk[eb + lane];
            cs = m.x; wvi = m.y;
        }
        int j = 0;
        for (; j + 7 < nb; j += 8) {
            int s0 = __builtin_amdgcn_readlane(cs, j);
            int s1 = __builtin_amdgcn_readlane(cs, j + 1);
            int s2 = __builtin_amdgcn_readlane(cs, j + 2);
            int s3 = __builtin_amdgcn_readlane(cs, j + 3);
            int s4 = __builtin_amdgcn_readlane(cs, j + 4);
            int s5 = __builtin_amdgcn_readlane(cs, j + 5);
            int s6 = __builtin_amdgcn_readlane(cs, j + 6);
            int s7 = __builtin_amdgcn_readlane(cs, j + 7);
            float w0 = __builtin_bit_cast(float, __builtin_amdgcn_readlane(wvi, j));
            float w1 = __builtin_bit_cast(float, __builtin_amdgcn_readlane(wvi, j + 1));
            float w2 = __builtin_bit_cast(float, __builtin_amdgcn_readlane(wvi, j + 2));
            float w3 = __builtin_bit_cast(float, __builtin_amdgcn_readlane(wvi, j + 3));
            float w4 = __builtin_bit_cast(float, __builtin_amdgcn_readlane(wvi, j + 4));
            float w5 = __builtin_bit_cast(float, __builtin_amdgcn_readlane(wvi, j + 5));
            float w6 = __builtin_bit_cast(float, __builtin_amdgcn_readlane(wvi, j + 6));
            float w7 = __builtin_bit_cast(float, __builtin_amdgcn_readlane(wvi, j + 7));
            unsigned u0 = ((const unsigned*)(carry + ((size_t)s0 << 7)))[lane];
            unsigned u1 = ((const unsigned*)(carry + ((size_t)s1 << 7)))[lane];
            unsigned u2 = ((const unsigned*)(carry + ((size_t)s2 << 7)))[lane];
            unsigned u3 = ((const unsigned*)(carry + ((size_t)s3 << 7)))[lane];
            unsigned u4 = ((const unsigned*)(carry + ((size_t)s4 << 7)))[lane];
            unsigned u5 = ((const unsigned*)(carry + ((size_t)s5 << 7)))[lane];
            unsigned u6 = ((const unsigned*)(carry + ((size_t)s6 << 7)))[lane];
            unsigned u7 = ((const unsigned*)(carry + ((size_t)s7 << 7)))[lane];
            a0x = fmaf(w0, bflo(u0), a0x); a0y = fmaf(w0, bfhi(u0), a0y);
            a1x = fmaf(w1, bflo(u1), a1x); a1y = fmaf(w1, bfhi(u1), a1y);
            a2x = fmaf(w2, bflo(u2), a2x); a2y = fmaf(w2, bfhi(u2), a2y);
            a3x = fmaf(w3, bflo(u3), a3x); a3y = fmaf(w3, bfhi(u3), a3y);
            a0x = fmaf(w4, bflo(u4), a0x); a0y = fmaf(w4, bfhi(u4), a0y);
            a1x = fmaf(w5, bflo(u5), a1x); a1y = fmaf(w5, bfhi(u5), a1y);
            a2x = fmaf(w6, bflo(u6), a2x); a2y = fmaf(w6, bfhi(u6), a2y);
            a3x = fmaf(w7, bflo(u7), a3x); a3y = fmaf(w7, bfhi(u7), a3y);
        }
        for (; j + 3 < nb; j += 4) {
            int s0 = __builtin_amdgcn_readlane(cs, j);
            int s1 = __builtin_amdgcn_readlane(cs, j + 1);
            int s2 = __builtin_amdgcn_readlane(cs, j + 2);
            int s3 = __builtin_amdgcn_readlane(cs, j + 3);
            float w0 = __builtin_bit_cast(float, __builtin_amdgcn_readlane(wvi, j));
            float w1 = __builtin_bit_cast(float, __builtin_amdgcn_readlane(wvi, j + 1));
            float w2 = __builtin_bit_cast(float, __builtin_amdgcn_readlane(wvi, j + 2));
            float w3 = __builtin_bit_cast(float, __builtin_amdgcn_readlane(wvi, j + 3));
            unsigned u0 = ((const unsigned*)(carry + ((size_t)s0 << 7)))[lane];
            unsigned u1 = ((const unsigned*)(carry + ((size_t)s1 << 7)))[lane];
            unsigned u2 = ((const unsigned*)(carry + ((size_t)s2 << 7)))[lane];
            unsigned u3 = ((const unsigned*)(carry + ((size_t)s3 << 7)))[lane];
            a0x = fmaf(w0, bflo(u0), a0x); a0y = fmaf(w0, bfhi(u0), a0y);
            a1x = fmaf(w1, bflo(u1), a1x); a1y = fmaf(w1, bfhi(u1), a1y);
            a2x = fmaf(w2, bflo(u2), a2x); a2y = fmaf(w2, bfhi(u2), a2y);
            a3x = fmaf(w3, bflo(u3), a3x); a3y = fmaf(w3, bfhi(u3), a3y);
        }
        for (; j < nb; ++j) {
            int s0 = __builtin_amdgcn_readlane(cs, j);
            float w0 = __builtin_bit_cast(float, __builtin_amdgcn_readlane(wvi, j));
            unsigned u0 = ((const unsigned*)(carry + ((size_t)s0 << 7)))[lane];
            a0x = fmaf(w0, bflo(u0), a0x); a0y = fmaf(w0, bfhi(u0), a0y);
        }
    }

    unsigned ux = ((const unsigned*)(c0 + ((size_t)node << 7)))[lane];
    float vx = (1.f - ALPHA) * (a0x + a1x + a2x + a3x) + ALPHA * bflo(ux);
    float vy = (1.f - ALPHA) * (a0y + a1y + a2y + a3y) + ALPHA * bfhi(ux);

    if (FINAL) {
        float mx = fmaxf(vx, vy);
#pragma unroll
        for (int off = 32; off; off >>= 1) mx = fmaxf(mx, __shfl_xor(mx, off, 64));
        float se = __expf(vx - mx) + __expf(vy - mx);
#pragma unroll
        for (int off = 32; off; off >>= 1) se += __shfl_xor(se, off, 64);
        float l = mx + __logf(se);
        float2 o; o.x = vx - l; o.y = vy - l;
        ((float2*)(outf + ((size_t)node << 7)))[lane] = o;
    } else {
        unsigned o = (unsigned)f2bf(vx) | ((unsigned)f2bf(vy) << 16);
        ((unsigned*)(outb + ((size_t)node << 7)))[lane] = o;
    }
}

// ---------------------------------------------------------------------------

extern "C" void kernel_launch(void* const* d_in, const int* in_sizes, int n_in,
                              void* d_out, int out_size, void* d_ws, size_t ws_size,
                              hipStream_t stream) {
    const float* x   = (const float*)d_in[0];
    const int*   ei  = (const int*)d_in[1];
    const float* ew  = (const float*)d_in[2];
    const float* W1  = (const float*)d_in[3];
    const float* b1  = (const float*)d_in[4];
    const float* W2  = (const float*)d_in[5];
    const float* b2  = (const float*)d_in[6];
    float* outp = (float*)d_out;

    const int E = in_sizes[1] / 2;
    const int Nn = N_NODES;
    const int* srcv = ei;
    const int* dstv = ei + E;
    const size_t NC = (size_t)Nn * NCLASS;   // 12.8M elements

    // workspace layout (16B-aligned buffers)
    unsigned short* c0  = (unsigned short*)d_ws;    // bf16 x0 copy     [NC]
    unsigned short* A16 = c0 + NC;                  // ping             [NC]
    unsigned short* B16 = A16 + NC;                 // pong             [NC]
    unsigned short* hb  = A16;                      // H bf16 overlay (dead before hops)
    unsigned short* w1t = B16 + NC;                 // 256x512
    unsigned short* w2t = w1t + NHID * NFEAT;       // 128x256
    int* row_ptr = (int*)(w2t + NCLASS * NHID);     // Nn+1
    int* fill    = row_ptr + (Nn + 1);              // Nn (counts)
    int* partial = fill + Nn;                       // 128
    int2* epk    = (int2*)(partial + 128);          // E packed {src, w}

    const int NB = (Nn + 1023) / 1024;              // 98 scan blocks

    // ---- CSR build ----
    hipMemsetAsync(fill, 0, (size_t)Nn * sizeof(int), stream);
    count_kernel<<<(E + 255) / 256, 256, 0, stream>>>(dstv, fill, E);
    scan_p1<<<NB, 256, 0, stream>>>(fill, partial, Nn);
    scan_p2<<<1, 128, 0, stream>>>(partial, NB);
    scan_p3<<<NB, 256, 0, stream>>>(fill, partial, row_ptr, fill, Nn);
    scatter_kernel<<<(E + 255) / 256, 256, 0, stream>>>(srcv, dstv, ew, fill, epk, E);

    // ---- weight prep ----
    wtrans_kernel<<<(NHID * NFEAT + 255) / 256, 256, 0, stream>>>(W1, w1t, NFEAT, NHID);
    wtrans_kernel<<<(NCLASS * NHID + 255) / 256, 256, 0, stream>>>(W2, w2t, NHID, NCLASS);

    // ---- MLP (bf16 MFMA) ----
    {
        gemm1_cont<<<(Nn + 127) / 128, 512, 0, stream>>>(x, w1t, b1, hb, Nn);
        gemm2_m97<<<(Nn + 127) / 128, 256, 0, stream>>>(hb, w2t, b2, c0, Nn);
    }

    // ---- K_HOPS propagation (bf16 carry), ping-pong; last hop fuses softmax ----
    int grid = (Nn + 3) / 4;
    const unsigned short* carry = c0;
    unsigned short* dsts[2] = {A16, B16};
    for (int k = 0; k < K_HOPS - 1; ++k) {
        unsigned short* o = dsts[k & 1];
        hop_kernel<0><<<grid, 256, 0, stream>>>(carry, c0, row_ptr, epk, o, nullptr, Nn);
        carry = o;
    }
    hop_kernel<1><<<grid, 256, 0, stream>>>(carry, c0, row_ptr, epk, nullptr, outp, Nn);
}

// Round 11
// 600.945 us; speedup vs baseline: 1.1499x; 1.0736x over previous
//
#include <hip/hip_runtime.h>
#include <hip/hip_bf16.h>
#include <cstdint>
#include <cstddef>

#define N_NODES 100000
#define NFEAT 512
#define NHID 256
#define NCLASS 128
#define K_HOPS 5
#define ALPHA 0.1f

#define BKT_SHIFT 8                       // 256 nodes per bucket
#define NBKT ((N_NODES + 255) >> 8)       // 391
#define EPB 4096                          // edges per pass-B block

typedef __attribute__((ext_vector_type(8))) short short8v;   // 8 bf16 (4 VGPRs)
typedef __attribute__((ext_vector_type(4))) float f32x4;     // MFMA accumulator

__device__ __forceinline__ unsigned short f2bf(float f) {
    unsigned u = __builtin_bit_cast(unsigned, f);
    u += 0x7FFFu + ((u >> 16) & 1u);      // round-to-nearest-even
    return (unsigned short)(u >> 16);
}
__device__ __forceinline__ float bflo(unsigned u) {
    return __builtin_bit_cast(float, u << 16);
}
__device__ __forceinline__ float bfhi(unsigned u) {
    return __builtin_bit_cast(float, u & 0xFFFF0000u);
}
__device__ __forceinline__ unsigned cvtpk2(float a, float b) {
    unsigned r;
    asm("v_cvt_pk_bf16_f32 %0, %1, %2" : "=v"(r) : "v"(a), "v"(b));
    return r;   // low16 = bf16(a), high16 = bf16(b)
}
__device__ __forceinline__ void gload_lds16(const void* g, void* l) {
    __builtin_amdgcn_global_load_lds((const __attribute__((address_space(1))) void*)g,
                                     (__attribute__((address_space(3))) void*)l, 16, 0, 0);
}

// ---------------------------------------------------------------------------
// CSR build: histogram -> hierarchical scan -> bucketed 2-pass scatter
// ---------------------------------------------------------------------------

__global__ void count_kernel(const int* __restrict__ dst, int* __restrict__ counts, int E) {
    int i = blockIdx.x * blockDim.x + threadIdx.x;
    if (i < E) atomicAdd(&counts[dst[i]], 1);
}

__global__ __launch_bounds__(256) void scan_p1(const int* __restrict__ counts,
                                               int* __restrict__ partial, int n) {
    __shared__ int ws[4];
    int b = blockIdx.x, t = threadIdx.x;
    int base = b * 1024 + t * 4;
    int s = 0;
#pragma unroll
    for (int j = 0; j < 4; ++j) {
        int idx = base + j;
        if (idx < n) s += counts[idx];
    }
#pragma unroll
    for (int off = 32; off; off >>= 1) s += __shfl_xor(s, off, 64);
    if ((t & 63) == 0) ws[t >> 6] = s;
    __syncthreads();
    if (t == 0) partial[b] = ws[0] + ws[1] + ws[2] + ws[3];
}

__global__ __launch_bounds__(128) void scan_p2(int* __restrict__ partial, int nb) {
    __shared__ int s[128];
    int t = threadIdx.x;
    int v = (t < nb) ? partial[t] : 0;
    s[t] = v;
    __syncthreads();
    for (int off = 1; off < 128; off <<= 1) {
        int u = (t >= off) ? s[t - off] : 0;
        __syncthreads();
        s[t] += u;
        __syncthreads();
    }
    if (t < nb) partial[t] = (t == 0) ? 0 : s[t - 1];
}

__global__ __launch_bounds__(256) void scan_p3(const int* __restrict__ counts,
                                               const int* __restrict__ partial,
                                               int* __restrict__ row_ptr,
                                               int* __restrict__ fill, int n) {
    __shared__ int ts[256];
    int b = blockIdx.x, t = threadIdx.x;
    int base = b * 1024 + t * 4;
    int c[4];
#pragma unroll
    for (int j = 0; j < 4; ++j) {
        int idx = base + j;
        c[j] = (idx < n) ? counts[idx] : 0;
    }
    int s = c[0] + c[1] + c[2] + c[3];
    ts[t] = s;
    __syncthreads();
    for (int off = 1; off < 256; off <<= 1) {
        int v = (t >= off) ? ts[t - off] : 0;
        __syncthreads();
        ts[t] += v;
        __syncthreads();
    }
    int pre = partial[b] + ((t == 0) ? 0 : ts[t - 1]);
#pragma unroll
    for (int j = 0; j < 4; ++j) {
        int idx = base + j;
        if (idx < n) {
            row_ptr[idx] = pre;
            fill[idx] = pre;
            if (idx == n - 1) row_ptr[n] = pre + c[j];
            pre += c[j];
        }
    }
}

// bktfill[b] = row_ptr[b << BKT_SHIFT]  (bucket windows in ebk == in epk)
__global__ void bkt_init(const int* __restrict__ row_ptr, int* __restrict__ bktfill,
                         int nbkt, int nnodes) {
    int i = blockIdx.x * blockDim.x + threadIdx.x;
    if (i < nbkt) {
        int nd = i << BKT_SHIFT; if (nd > nnodes) nd = nnodes;
        bktfill[i] = row_ptr[nd];
    }
}

// Pass B: bucket the edges. Per block: LDS histogram over NBKT buckets, one
// global atomicAdd reservation per touched bucket, then write each edge into
// its block-contiguous run. Runs (~10 x 12B) assemble whole lines in this
// CU's cache -> writeback ~once (vs 64B/entry for the old global scatter).
__global__ __launch_bounds__(256) void bucket_scatter(const int* __restrict__ src,
                                                      const int* __restrict__ dst,
                                                      const float* __restrict__ w,
                                                      int* __restrict__ bktfill,
                                                      int2* __restrict__ ebk_sw,
                                                      int* __restrict__ ebk_d, int E) {
    __shared__ int hist[NBKT];
    __shared__ int base[NBKT];
    const int t = threadIdx.x;
    const int e0 = blockIdx.x * EPB;

    for (int i = t; i < NBKT; i += 256) hist[i] = 0;
    __syncthreads();

    int myd[16], mys[16], myw[16];
    int cnt = 0;
#pragma unroll
    for (int j = 0; j < 16; ++j) {
        int i = e0 + j * 256 + t;
        if (i < E) {
            myd[j] = dst[i]; mys[j] = src[i];
            myw[j] = __builtin_bit_cast(int, w[i]);
            atomicAdd(&hist[myd[j] >> BKT_SHIFT], 1);
            cnt = j + 1;
        }
    }
    __syncthreads();
    for (int i = t; i < NBKT; i += 256) {
        int c = hist[i];
        base[i] = c ? atomicAdd(&bktfill[i], c) : 0;
        hist[i] = 0;                    // reuse as local fill
    }
    __syncthreads();
    for (int j = 0; j < cnt; ++j) {
        int b = myd[j] >> BKT_SHIFT;
        int r = atomicAdd(&hist[b], 1);
        int g = base[b] + r;
        int2 sw; sw.x = mys[j]; sw.y = myw[j];
        ebk_sw[g] = sw;
        ebk_d[g] = myd[j];
    }
}

// Pass C: one block per bucket. The bucket's epk window (~32KB) and fill
// slice (1KB) stay in this block's XCD L2 -> random writes never leave it.
__global__ __launch_bounds__(256) void final_scatter(const int* __restrict__ row_ptr,
                                                     const int2* __restrict__ ebk_sw,
                                                     const int* __restrict__ ebk_d,
                                                     int* __restrict__ fill,
                                                     int2* __restrict__ epk, int nnodes) {
    int b = blockIdx.x;
    int n0 = b << BKT_SHIFT;
    int n1 = n0 + (1 << BKT_SHIFT); if (n1 > nnodes) n1 = nnodes;
    int s = row_ptr[n0], e = row_ptr[n1];
    for (int i = s + threadIdx.x; i < e; i += 256) {
        int d = ebk_d[i];
        int pos = atomicAdd(&fill[d], 1);
        epk[pos] = ebk_sw[i];
    }
}

// ---------------------------------------------------------------------------
// Weight transpose + bf16 convert: Wt[n][k] = bf16(W[k][n])
// ---------------------------------------------------------------------------
__global__ void wtrans_kernel(const float* __restrict__ W, unsigned short* __restrict__ Wt,
                              int K, int N) {
    int idx = blockIdx.x * blockDim.x + threadIdx.x;
    if (idx >= N * K) return;
    int n = idx / K, k = idx - n * K;
    Wt[idx] = f2bf(W[(size_t)k * N + n]);
}

// ---------------------------------------------------------------------------
// GEMM layer 1 (unchanged from R10, ~125us): contiguous-row A staging +
// XOR-swizzled LDS. Hb[M][256] = relu(X[M][512] @ W1t^T + b1)
// ---------------------------------------------------------------------------
__global__ __launch_bounds__(512) void gemm1_cont(const float* __restrict__ X,
                                                  const unsigned short* __restrict__ W1t,
                                                  const float* __restrict__ b1,
                                                  unsigned short* __restrict__ Hb, int M) {
    __shared__ char smem[32768];
    char* const Abuf = smem;           // 16KB: [128 rows][128B] swizzled f32
    char* const Bbuf = smem + 16384;   // 16KB: frag-major bf16, 256 cols

    const int tid = threadIdx.x;
    const int lane = tid & 63;
    const int wv = tid >> 6;           // 0..7
    const int wr = wv >> 2, wc = wv & 3;
    const int brow = blockIdx.x * 128;

    const char* asrc[2];
    int adst[2];
#pragma unroll
    for (int c = 0; c < 2; ++c) {
        int row = c * 64 + wv * 8 + (lane >> 3);
        int ar = brow + row; if (ar > M - 1) ar = M - 1;
        int kb = ((lane & 7) << 4) ^ ((lane >> 3) << 4);
        asrc[c] = (const char*)X + (size_t)ar * (NFEAT * 4) + kb;
        adst[c] = c * 8192 + wv * 1024;
    }
    const char* bsrc[2];
    int bdst[2];
#pragma unroll
    for (int c = 0; c < 2; ++c) {
        int ci = wv + c * 8;
        int col = ci * 16 + (lane & 15);
        bsrc[c] = (const char*)&W1t[(size_t)col * NFEAT + (lane >> 4) * 8];
        bdst[c] = ci * 1024;
    }

    f32x4 acc[4][4];
#pragma unroll
    for (int m = 0; m < 4; ++m)
#pragma unroll
        for (int n = 0; n < 4; ++n) acc[m][n] = f32x4{0.f, 0.f, 0.f, 0.f};

    for (int s = 0; s < NFEAT / 32; ++s) {
#pragma unroll
        for (int c = 0; c < 2; ++c)
            gload_lds16(asrc[c] + (size_t)s * 128, Abuf + adst[c]);
#pragma unroll
        for (int c = 0; c < 2; ++c)
            gload_lds16(bsrc[c] + (size_t)s * 64, Bbuf + bdst[c]);
        asm volatile("s_waitcnt vmcnt(0)" ::: "memory");
        __syncthreads();

        short8v a[4], b[4];
#pragma unroll
        for (int m = 0; m < 4; ++m) {
            int row = wr * 64 + m * 16 + (lane & 15);
            int s4 = (row & 7) << 4;
            int kb = (lane >> 4) * 32;
            f32x4 lo = *(const f32x4*)(Abuf + row * 128 + ((kb + 0) ^ s4));
            f32x4 hi = *(const f32x4*)(Abuf + row * 128 + ((kb + 16) ^ s4));
            uint4 u;
            u.x = cvtpk2(lo[0], lo[1]); u.y = cvtpk2(lo[2], lo[3]);
            u.z = cvtpk2(hi[0], hi[1]); u.w = cvtpk2(hi[2], hi[3]);
            a[m] = __builtin_bit_cast(short8v, u);
        }
#pragma unroll
        for (int n = 0; n < 4; ++n)
            b[n] = *(const short8v*)(Bbuf + ((wc * 4 + n) * 64 + lane) * 16);
#pragma unroll
        for (int m = 0; m < 4; ++m)
#pragma unroll
            for (int n = 0; n < 4; ++n)
                acc[m][n] = __builtin_amdgcn_mfma_f32_16x16x32_bf16(a[m], b[n], acc[m][n], 0, 0, 0);
        __syncthreads();
    }

#pragma unroll
    for (int n = 0; n < 4; ++n) {
        int colg = wc * 64 + n * 16 + (lane & 15);
        float bv = b1[colg];
#pragma unroll
        for (int m = 0; m < 4; ++m) {
#pragma unroll
            for (int r = 0; r < 4; ++r) {
                int rowg = brow + wr * 64 + m * 16 + (lane >> 4) * 4 + r;
                if (rowg < M) {
                    float v = fmaxf(acc[m][n][r] + bv, 0.f);
                    Hb[(size_t)rowg * NHID + colg] = f2bf(v);
                }
            }
        }
    }
}

// ---------------------------------------------------------------------------
// GEMM layer 2 (unchanged, ~25us): C0[M][128] = Hb[M][256] @ W2t^T + b2
// ---------------------------------------------------------------------------
__global__ __launch_bounds__(256) void gemm2_m97(const unsigned short* __restrict__ Hb,
                                                 const unsigned short* __restrict__ W2t,
                                                 const float* __restrict__ b2,
                                                 unsigned short* __restrict__ C0, int M) {
    __shared__ char smem[16384];           // A 8KB + B 8KB
    char* const Abuf = smem;
    char* const Bbuf = smem + 8192;

    const int tid = threadIdx.x;
    const int lane = tid & 63;
    const int wv = tid >> 6;               // 0..3
    const int wr = wv >> 1, wc = wv & 1;
    const int brow = blockIdx.x * 128;

    const char* asrc[2];
    const char* bsrc[2];
    int cdst[2];
#pragma unroll
    for (int c = 0; c < 2; ++c) {
        int ci = wv + c * 4;               // 0..7
        int ar = brow + ci * 16 + (lane & 15); if (ar > M - 1) ar = M - 1;
        asrc[c] = (const char*)&Hb[(size_t)ar * NHID + (lane >> 4) * 8];
        int col = ci * 16 + (lane & 15);
        bsrc[c] = (const char*)&W2t[(size_t)col * NHID + (lane >> 4) * 8];
        cdst[c] = ci * 1024;
    }

    f32x4 acc[4][4];
#pragma unroll
    for (int m = 0; m < 4; ++m)
#pragma unroll
        for (int n = 0; n < 4; ++n) acc[m][n] = f32x4{0.f, 0.f, 0.f, 0.f};

    for (int s = 0; s < NHID / 32; ++s) {
#pragma unroll
        for (int c = 0; c < 2; ++c) {
            gload_lds16(asrc[c] + (size_t)s * 64, Abuf + cdst[c]);
            gload_lds16(bsrc[c] + (size_t)s * 64, Bbuf + cdst[c]);
        }
        asm volatile("s_waitcnt vmcnt(0)" ::: "memory");
        __syncthreads();

        short8v a[4], b[4];
#pragma unroll
        for (int m = 0; m < 4; ++m)
            a[m] = *(const short8v*)(Abuf + ((wr * 4 + m) * 64 + lane) * 16);
#pragma unroll
        for (int n = 0; n < 4; ++n)
            b[n] = *(const short8v*)(Bbuf + ((wc * 4 + n) * 64 + lane) * 16);
#pragma unroll
        for (int m = 0; m < 4; ++m)
#pragma unroll
            for (int n = 0; n < 4; ++n)
                acc[m][n] = __builtin_amdgcn_mfma_f32_16x16x32_bf16(a[m], b[n], acc[m][n], 0, 0, 0);
        __syncthreads();
    }

#pragma unroll
    for (int n = 0; n < 4; ++n) {
        int colg = wc * 64 + n * 16 + (lane & 15);
        float bv = b2[colg];
#pragma unroll
        for (int m = 0; m < 4; ++m) {
#pragma unroll
            for (int r = 0; r < 4; ++r) {
                int rowg = brow + wr * 64 + m * 16 + (lane >> 4) * 4 + r;
                if (rowg < M)
                    C0[(size_t)rowg * NCLASS + colg] = f2bf(acc[m][n][r] + bv);
            }
        }
    }
}

// ---------------------------------------------------------------------------
// One propagation hop (unchanged R5 structure). FINAL=1 fuses log-softmax.
// ---------------------------------------------------------------------------
template<int FINAL>
__global__ __launch_bounds__(256) void hop_kernel(const unsigned short* __restrict__ carry,
                                                  const unsigned short* __restrict__ c0,
                                                  const int* __restrict__ rp,
                                                  const int2* __restrict__ epk,
                                                  unsigned short* __restrict__ outb,
                                                  float* __restrict__ outf, int nnodes) {
    int node = blockIdx.x * 4 + (threadIdx.x >> 6);
    if (node >= nnodes) return;
    int lane = threadIdx.x & 63;
    int e0 = rp[node], e1 = rp[node + 1];

    float a0x = 0.f, a0y = 0.f, a1x = 0.f, a1y = 0.f;
    float a2x = 0.f, a2y = 0.f, a3x = 0.f, a3y = 0.f;

    for (int eb = e0; eb < e1; eb += 64) {
        int nb = e1 - eb; if (nb > 64) nb = 64;
        int cs = 0, wvi = 0;
        if (lane < nb) {
            int2 m = epk[eb + lane];
            cs = m.x; wvi = m.y;
        }
        int j = 0;
        for (; j + 7 < nb; j += 8) {
            int s0 = __builtin_amdgcn_readlane(cs, j);
            int s1 = __builtin_amdgcn_readlane(cs, j + 1);
            int s2 = __builtin_amdgcn_readlane(cs, j + 2);
            int s3 = __builtin_amdgcn_readlane(cs, j + 3);
            int s4 = __builtin_amdgcn_readlane(cs, j + 4);
            int s5 = __builtin_amdgcn_readlane(cs, j + 5);
            int s6 = __builtin_amdgcn_readlane(cs, j + 6);
            int s7 = __builtin_amdgcn_readlane(cs, j + 7);
            float w0 = __builtin_bit_cast(float, __builtin_amdgcn_readlane(wvi, j));
            float w1 = __builtin_bit_cast(float, __builtin_amdgcn_readlane(wvi, j + 1));
            float w2 = __builtin_bit_cast(float, __builtin_amdgcn_readlane(wvi, j + 2));
            float w3 = __builtin_bit_cast(float, __builtin_amdgcn_readlane(wvi, j + 3));
            float w4 = __builtin_bit_cast(float, __builtin_amdgcn_readlane(wvi, j + 4));
            float w5 = __builtin_bit_cast(float, __builtin_amdgcn_readlane(wvi, j + 5));
            float w6 = __builtin_bit_cast(float, __builtin_amdgcn_readlane(wvi, j + 6));
            float w7 = __builtin_bit_cast(float, __builtin_amdgcn_readlane(wvi, j + 7));
            unsigned u0 = ((const unsigned*)(carry + ((size_t)s0 << 7)))[lane];
            unsigned u1 = ((const unsigned*)(carry + ((size_t)s1 << 7)))[lane];
            unsigned u2 = ((const unsigned*)(carry + ((size_t)s2 << 7)))[lane];
            unsigned u3 = ((const unsigned*)(carry + ((size_t)s3 << 7)))[lane];
            unsigned u4 = ((const unsigned*)(carry + ((size_t)s4 << 7)))[lane];
            unsigned u5 = ((const unsigned*)(carry + ((size_t)s5 << 7)))[lane];
            unsigned u6 = ((const unsigned*)(carry + ((size_t)s6 << 7)))[lane];
            unsigned u7 = ((const unsigned*)(carry + ((size_t)s7 << 7)))[lane];
            a0x = fmaf(w0, bflo(u0), a0x); a0y = fmaf(w0, bfhi(u0), a0y);
            a1x = fmaf(w1, bflo(u1), a1x); a1y = fmaf(w1, bfhi(u1), a1y);
            a2x = fmaf(w2, bflo(u2), a2x); a2y = fmaf(w2, bfhi(u2), a2y);
            a3x = fmaf(w3, bflo(u3), a3x); a3y = fmaf(w3, bfhi(u3), a3y);
            a0x = fmaf(w4, bflo(u4), a0x); a0y = fmaf(w4, bfhi(u4), a0y);
            a1x = fmaf(w5, bflo(u5), a1x); a1y = fmaf(w5, bfhi(u5), a1y);
            a2x = fmaf(w6, bflo(u6), a2x); a2y = fmaf(w6, bfhi(u6), a2y);
            a3x = fmaf(w7, bflo(u7), a3x); a3y = fmaf(w7, bfhi(u7), a3y);
        }
        for (; j + 3 < nb; j += 4) {
            int s0 = __builtin_amdgcn_readlane(cs, j);
            int s1 = __builtin_amdgcn_readlane(cs, j + 1);
            int s2 = __builtin_amdgcn_readlane(cs, j + 2);
            int s3 = __builtin_amdgcn_readlane(cs, j + 3);
            float w0 = __builtin_bit_cast(float, __builtin_amdgcn_readlane(wvi, j));
            float w1 = __builtin_bit_cast(float, __builtin_amdgcn_readlane(wvi, j + 1));
            float w2 = __builtin_bit_cast(float, __builtin_amdgcn_readlane(wvi, j + 2));
            float w3 = __builtin_bit_cast(float, __builtin_amdgcn_readlane(wvi, j + 3));
            unsigned u0 = ((const unsigned*)(carry + ((size_t)s0 << 7)))[lane];
            unsigned u1 = ((const unsigned*)(carry + ((size_t)s1 << 7)))[lane];
            unsigned u2 = ((const unsigned*)(carry + ((size_t)s2 << 7)))[lane];
            unsigned u3 = ((const unsigned*)(carry + ((size_t)s3 << 7)))[lane];
            a0x = fmaf(w0, bflo(u0), a0x); a0y = fmaf(w0, bfhi(u0), a0y);
            a1x = fmaf(w1, bflo(u1), a1x); a1y = fmaf(w1, bfhi(u1), a1y);
            a2x = fmaf(w2, bflo(u2), a2x); a2y = fmaf(w2, bfhi(u2), a2y);
            a3x = fmaf(w3, bflo(u3), a3x); a3y = fmaf(w3, bfhi(u3), a3y);
        }
        for (; j < nb; ++j) {
            int s0 = __builtin_amdgcn_readlane(cs, j);
            float w0 = __builtin_bit_cast(float, __builtin_amdgcn_readlane(wvi, j));
            unsigned u0 = ((const unsigned*)(carry + ((size_t)s0 << 7)))[lane];
            a0x = fmaf(w0, bflo(u0), a0x); a0y = fmaf(w0, bfhi(u0), a0y);
        }
    }

    unsigned ux = ((const unsigned*)(c0 + ((size_t)node << 7)))[lane];
    float vx = (1.f - ALPHA) * (a0x + a1x + a2x + a3x) + ALPHA * bflo(ux);
    float vy = (1.f - ALPHA) * (a0y + a1y + a2y + a3y) + ALPHA * bfhi(ux);

    if (FINAL) {
        float mx = fmaxf(vx, vy);
#pragma unroll
        for (int off = 32; off; off >>= 1) mx = fmaxf(mx, __shfl_xor(mx, off, 64));
        float se = __expf(vx - mx) + __expf(vy - mx);
#pragma unroll
        for (int off = 32; off; off >>= 1) se += __shfl_xor(se, off, 64);
        float l = mx + __logf(se);
        float2 o; o.x = vx - l; o.y = vy - l;
        ((float2*)(outf + ((size_t)node << 7)))[lane] = o;
    } else {
        unsigned o = (unsigned)f2bf(vx) | ((unsigned)f2bf(vy) << 16);
        ((unsigned*)(outb + ((size_t)node << 7)))[lane] = o;
    }
}

// ---------------------------------------------------------------------------

extern "C" void kernel_launch(void* const* d_in, const int* in_sizes, int n_in,
                              void* d_out, int out_size, void* d_ws, size_t ws_size,
                              hipStream_t stream) {
    const float* x   = (const float*)d_in[0];
    const int*   ei  = (const int*)d_in[1];
    const float* ew  = (const float*)d_in[2];
    const float* W1  = (const float*)d_in[3];
    const float* b1  = (const float*)d_in[4];
    const float* W2  = (const float*)d_in[5];
    const float* b2  = (const float*)d_in[6];
    float* outp = (float*)d_out;

    const int E = in_sizes[1] / 2;
    const int Nn = N_NODES;
    const int* srcv = ei;
    const int* dstv = ei + E;
    const size_t NC = (size_t)Nn * NCLASS;   // 12.8M elements

    // workspace layout (16B-aligned buffers)
    unsigned short* c0  = (unsigned short*)d_ws;    // bf16 x0 copy     [NC]
    unsigned short* A16 = c0 + NC;                  // ping             [NC]
    unsigned short* B16 = A16 + NC;                 // pong             [NC]
    unsigned short* hb  = A16;                      // H bf16 overlay (MLP phase)
    int2* ebk_sw = (int2*)A16;                      // bucketed {src,w} overlay (CSR phase)
    int*  ebk_d  = (int*)B16;                       // bucketed dst overlay (CSR phase)
    unsigned short* w1t = B16 + NC;                 // 256x512
    unsigned short* w2t = w1t + NHID * NFEAT;       // 128x256
    int* row_ptr = (int*)(w2t + NCLASS * NHID);     // Nn+1
    int* fill    = row_ptr + (Nn + 1);              // Nn (counts)
    int* partial = fill + Nn;                       // 128
    int2* epk    = (int2*)(partial + 128);          // E packed {src, w}
    int* bktfill = (int*)(epk + E);                 // NBKT

    const int NB = (Nn + 1023) / 1024;              // 98 scan blocks
    const int NBLK_B = (E + EPB - 1) / EPB;         // 391 pass-B blocks

    // ---- CSR build (bucketed) ----
    hipMemsetAsync(fill, 0, (size_t)Nn * sizeof(int), stream);
    count_kernel<<<(E + 255) / 256, 256, 0, stream>>>(dstv, fill, E);
    scan_p1<<<NB, 256, 0, stream>>>(fill, partial, Nn);
    scan_p2<<<1, 128, 0, stream>>>(partial, NB);
    scan_p3<<<NB, 256, 0, stream>>>(fill, partial, row_ptr, fill, Nn);
    bkt_init<<<(NBKT + 255) / 256, 256, 0, stream>>>(row_ptr, bktfill, NBKT, Nn);
    bucket_scatter<<<NBLK_B, 256, 0, stream>>>(srcv, dstv, ew, bktfill, ebk_sw, ebk_d, E);
    final_scatter<<<NBKT, 256, 0, stream>>>(row_ptr, ebk_sw, ebk_d, fill, epk, Nn);

    // ---- weight prep ----
    wtrans_kernel<<<(NHID * NFEAT + 255) / 256, 256, 0, stream>>>(W1, w1t, NFEAT, NHID);
    wtrans_kernel<<<(NCLASS * NHID + 255) / 256, 256, 0, stream>>>(W2, w2t, NHID, NCLASS);

    // ---- MLP (bf16 MFMA) — hb overlays the (now dead) ebk buffers ----
    {
        gemm1_cont<<<(Nn + 127) / 128, 512, 0, stream>>>(x, w1t, b1, hb, Nn);
        gemm2_m97<<<(Nn + 127) / 128, 256, 0, stream>>>(hb, w2t, b2, c0, Nn);
    }

    // ---- K_HOPS propagation (bf16 carry), ping-pong; last hop fuses softmax ----
    int grid = (Nn + 3) / 4;
    const unsigned short* carry = c0;
    unsigned short* dsts[2] = {A16, B16};
    for (int k = 0; k < K_HOPS - 1; ++k) {
        unsigned short* o = dsts[k & 1];
        hop_kernel<0><<<grid, 256, 0, stream>>>(carry, c0, row_ptr, epk, o, nullptr, Nn);
        carry = o;
    }
    hop_kernel<1><<<grid, 256, 0, stream>>>(carry, c0, row_ptr, epk, nullptr, outp, Nn);
}